// Round 3
// baseline (869.731 us; speedup 1.0000x reference)
//
#include <hip/hip_runtime.h>

// Problem constants (B,C,T,V)=(32,128,64,25), N_STEP=8, DILATION=1
#define CC     128
#define TT     64
#define VV     25
#define BB     32
#define PP     (TT * VV)          // 1600 positions per (b, c)
#define CHUNK  (BB * CC * PP)     // 6,553,600 elems per output chunk
#define NSTEP  8
#define PTILE  64                 // positions per block tile
#define NPT    (PP / PTILE)       // 25 tiles per batch

typedef __attribute__((ext_vector_type(8))) __bf16 bf16x8;   // MFMA A/B frag (4 VGPR)
typedef __attribute__((ext_vector_type(4))) float  f32x4;    // MFMA C/D frag
typedef __attribute__((ext_vector_type(2))) float  f32x2;

__device__ __forceinline__ float fast_tanh(float x) {
    float e = __expf(2.0f * x);
    return 1.0f - 2.0f * __builtin_amdgcn_rcpf(e + 1.0f);
}

// Split fp32 into truncated-bf16 hi + truncated-bf16 lo (residual <= 2^-16 rel).
__device__ __forceinline__ void bf16_split(float y, unsigned short& h, unsigned short& lo) {
    unsigned int bits = __float_as_uint(y);
    h = (unsigned short)(bits >> 16);
    float r = y - __uint_as_float(bits & 0xffff0000u);
    lo = (unsigned short)(__float_as_uint(r) >> 16);
}

// Byte offset of (p, c) in a [PTILE][CC] ushort LDS plane, XOR-swizzled so both
// the strided b128 A-frag reads and the scalar b16 publishes stay bank-balanced.
__device__ __forceinline__ int xb_off(int p, int c) {
    return (p * 256 + c * 2) ^ ((p & 7) << 4) ^ ((p & 8) << 3);
}

// LDS-only barrier: waits own DS ops, does NOT drain vmcnt (global stores stay
// in flight across steps). sched_barrier fences per guide rule #18.
__device__ __forceinline__ void lds_barrier() {
    asm volatile("s_waitcnt lgkmcnt(0)" ::: "memory");
    __builtin_amdgcn_sched_barrier(0);
    __builtin_amdgcn_s_barrier();
    __builtin_amdgcn_sched_barrier(0);
}

// ---- single fused kernel: 8-step Euler, split-bf16 MFMA, swapped operands ----
// Block owns (b, 64-position tile) x all 128 channels. D = X^T * W^T: row = p,
// col = d; each lane holds 4 consecutive positions -> float4 global stores.
// fp32 state in registers; bf16 hi/lo state double-buffered in LDS (64 KB).
// Wave w: d-tiles {2w,2w+1} x p-tiles {0..3} = 8 acc tiles, 96 MFMA/step.
__global__ __launch_bounds__(256) void euler_fused(
    const float* __restrict__ z, const float* __restrict__ W,
    const float* __restrict__ bias, float* __restrict__ out)
{
    __shared__ unsigned short XH[2][PTILE * CC];    // 2 x 16 KB bf16-hi state
    __shared__ unsigned short XL[2][PTILE * CC];    // 2 x 16 KB bf16-lo state

    const int b   = blockIdx.y;
    const int p0  = blockIdx.x * PTILE;
    const int tid = threadIdx.x;
    const int w   = tid >> 6;          // wave 0..3 -> d-tiles {2w, 2w+1}
    const int lr  = tid & 15;          // lane&15: B-col (=d) / A-row (=p) / D-col
    const int lh  = (tid >> 4) & 3;    // lane>>4: k-group / D-row-group

    // ---- W fragments split in-register from fp32 (no separate wsplit kernel).
    // B operand: B[k=c][col=d] = W[d][c]; lane needs W[d][cb..cb+7] hi+lo.
    union BF8 { bf16x8 v; unsigned short u[8]; };
    bf16x8 wh[2][4], wl[2][4];
    #pragma unroll
    for (int dt = 0; dt < 2; ++dt) {
        const int d = (2 * w + dt) * 16 + lr;
        #pragma unroll
        for (int ks = 0; ks < 4; ++ks) {
            const float* wp = W + d * CC + ks * 32 + lh * 8;
            f32x4 f0 = *(const f32x4*)wp;
            f32x4 f1 = *(const f32x4*)(wp + 4);
            BF8 th, tl;
            #pragma unroll
            for (int e = 0; e < 4; ++e) bf16_split(f0[e], th.u[e],     tl.u[e]);
            #pragma unroll
            for (int e = 0; e < 4; ++e) bf16_split(f1[e], th.u[4 + e], tl.u[4 + e]);
            wh[dt][ks] = th.v;
            wl[dt][ks] = tl.v;
        }
    }

    // bias per D-column: one scalar per d-tile
    float bv[2];
    #pragma unroll
    for (int dt = 0; dt < 2; ++dt) bv[dt] = bias[(2 * w + dt) * 16 + lr];

    // ---- prologue: cooperative z-tile load -> chunk-0 outputs + XH/XL[0] ----
    const float* zb = z + (size_t)b * CC * PP + p0;
    #pragma unroll
    for (int it = 0; it < 8; ++it) {
        int slot = it * 256 + tid;                  // 2048 float4 slots
        int c  = slot >> 4;                         // 16 float4 per 64-pos row
        int po = (slot & 15) * 4;
        f32x4 v = *(const f32x4*)(zb + (size_t)c * PP + po);
        size_t o = (size_t)(b * CC + c) * PP + p0 + po;
        __builtin_nontemporal_store(v, (f32x4*)(out + o));                      // z_shift 0
        __builtin_nontemporal_store(v, (f32x4*)(out + (size_t)9 * CHUNK + o));  // z_cls 0
        #pragma unroll
        for (int e = 0; e < 4; ++e) {
            unsigned short h, lo;
            bf16_split(v[e], h, lo);
            int off = xb_off(po + e, c);
            *(unsigned short*)((char*)XH[0] + off) = h;
            *(unsigned short*)((char*)XL[0] + off) = lo;
        }
    }

    // ---- fp32 state in registers at this lane's D-layout slots:
    // st[pt][dt] = X[d=(2w+dt)*16+lr][p0 + pt*16 + lh*4 .. +3]
    f32x4 st[4][2];
    #pragma unroll
    for (int pt = 0; pt < 4; ++pt)
        #pragma unroll
        for (int dt = 0; dt < 2; ++dt) {
            const int d = (2 * w + dt) * 16 + lr;
            st[pt][dt] = *(const f32x4*)(z + (size_t)(b * CC + d) * PP + p0 + pt * 16 + lh * 4);
        }

    lds_barrier();

    const int swz = ((lr & 7) << 4) ^ ((lr & 8) << 3);

    #pragma unroll
    for (int i = 1; i <= NSTEP; ++i) {
        const char* xh = (const char*)XH[(i - 1) & 1];
        const char* xl = (const char*)XL[(i - 1) & 1];

        f32x4 acc[4][2];
        #pragma unroll
        for (int pt = 0; pt < 4; ++pt)
            #pragma unroll
            for (int dt = 0; dt < 2; ++dt)
                acc[pt][dt] = (f32x4){0.0f, 0.0f, 0.0f, 0.0f};

        // ---- channel matmul: acc = Xh*Wh + Xl*Wh + Xh*Wl (fp32 accum) ----
        #pragma unroll
        for (int ks = 0; ks < 4; ++ks) {
            const int co = ks * 64 + lh * 16;
            bf16x8 ah[4], al[4];
            #pragma unroll
            for (int pt = 0; pt < 4; ++pt) {
                const int ro = ((pt * 16 + lr) * 256 + co) ^ swz;
                ah[pt] = *(const bf16x8*)(xh + ro);
                al[pt] = *(const bf16x8*)(xl + ro);
            }
            #pragma unroll
            for (int pt = 0; pt < 4; ++pt)
                #pragma unroll
                for (int dt = 0; dt < 2; ++dt) {
                    acc[pt][dt] = __builtin_amdgcn_mfma_f32_16x16x32_bf16(ah[pt], wh[dt][ks], acc[pt][dt], 0, 0, 0);
                    acc[pt][dt] = __builtin_amdgcn_mfma_f32_16x16x32_bf16(al[pt], wh[dt][ks], acc[pt][dt], 0, 0, 0);
                    acc[pt][dt] = __builtin_amdgcn_mfma_f32_16x16x32_bf16(ah[pt], wl[dt][ks], acc[pt][dt], 0, 0, 0);
                }
        }

        // ---- y = x_old + tanh(acc + bias); state stays in registers ----
        #pragma unroll
        for (int pt = 0; pt < 4; ++pt)
            #pragma unroll
            for (int dt = 0; dt < 2; ++dt)
                #pragma unroll
                for (int j = 0; j < 4; ++j)
                    st[pt][dt][j] += fast_tanh(acc[pt][dt][j] + bv[dt]);

        // ---- publish new bf16 hi/lo state into the WRITE buffer ----
        if (i < NSTEP) {
            char* yh = (char*)XH[i & 1];
            char* yl = (char*)XL[i & 1];
            #pragma unroll
            for (int pt = 0; pt < 4; ++pt)
                #pragma unroll
                for (int dt = 0; dt < 2; ++dt) {
                    const int d = (2 * w + dt) * 16 + lr;
                    #pragma unroll
                    for (int j = 0; j < 4; ++j) {
                        const int p = pt * 16 + lh * 4 + j;
                        unsigned short h, lo;
                        bf16_split(st[pt][dt][j], h, lo);
                        const int off = xb_off(p, d);
                        *(unsigned short*)(yh + off) = h;
                        *(unsigned short*)(yl + off) = lo;
                    }
                }
        }

        // ---- global stores for chunk i (nontemporal, fire-and-forget) ----
        const size_t shiftBase = (size_t)i * CHUNK;
        const size_t clsBase   = (size_t)(9 + i) * CHUNK;
        const int s = VV * i;   // flat-position shift (t -> t+i)
        const bool fast = (p0 >= s) && (p0 + PTILE - 1 + s < PP);   // block-uniform
        #pragma unroll
        for (int pt = 0; pt < 4; ++pt) {
            const int P0 = p0 + pt * 16 + lh * 4;
            #pragma unroll
            for (int dt = 0; dt < 2; ++dt) {
                const int d = (2 * w + dt) * 16 + lr;
                const size_t row = (size_t)(b * CC + d) * PP;
                f32x4 y = st[pt][dt];
                __builtin_nontemporal_store(y, (f32x4*)(out + clsBase + row + P0));  // z_cls
                if (fast) {
                    float* dst = out + shiftBase + row + P0 + s;
                    if ((i & 1) == 0) {          // s even -> 8B-aligned pairs
                        f32x2 y01 = {y[0], y[1]}, y23 = {y[2], y[3]};
                        __builtin_nontemporal_store(y01, (f32x2*)(dst));
                        __builtin_nontemporal_store(y23, (f32x2*)(dst + 2));
                    } else {
                        __builtin_nontemporal_store(y[0], dst);
                        __builtin_nontemporal_store(y[1], dst + 1);
                        __builtin_nontemporal_store(y[2], dst + 2);
                        __builtin_nontemporal_store(y[3], dst + 3);
                    }
                } else {
                    #pragma unroll
                    for (int e = 0; e < 4; ++e) {
                        const int p = P0 + e, q = p + s;
                        if (q < PP) __builtin_nontemporal_store(y[e], out + shiftBase + row + q);
                        if (p < s)  __builtin_nontemporal_store(0.0f, out + shiftBase + row + p);
                    }
                }
            }
        }

        if (i < NSTEP) lds_barrier();   // LDS-only: publish visible, stores in flight
    }
}

extern "C" void kernel_launch(void* const* d_in, const int* in_sizes, int n_in,
                              void* d_out, int out_size, void* d_ws, size_t ws_size,
                              hipStream_t stream) {
    const float* z    = (const float*)d_in[0];   // (32,128,64,25) fp32
    const float* W    = (const float*)d_in[1];   // (128,128) fp32
    const float* bias = (const float*)d_in[2];   // (128,) fp32
    float* out = (float*)d_out;                  // 18 * CHUNK fp32

    hipLaunchKernelGGL(euler_fused, dim3(NPT, BB), dim3(256), 0, stream, z, W, bias, out);
}

// Round 4
// 589.635 us; speedup vs baseline: 1.4750x; 1.4750x over previous
//
#include <hip/hip_runtime.h>

// Problem constants (B,C,T,V)=(32,128,64,25), N_STEP=8, DILATION=1
#define CC     128
#define TT     64
#define VV     25
#define BB     32
#define PP     (TT * VV)          // 1600 positions per (b, c)
#define CHUNK  (BB * CC * PP)     // 6,553,600 elems per output chunk
#define NSTEP  8
#define PTILE  64                 // positions per block tile
#define NPT    (PP / PTILE)       // 25 tiles per batch

typedef __attribute__((ext_vector_type(8))) __bf16 bf16x8;   // MFMA A/B frag (4 VGPR)
typedef __attribute__((ext_vector_type(4))) float  f32x4;    // MFMA C/D frag

__device__ __forceinline__ float fast_tanh(float x) {
    float e = __expf(2.0f * x);
    return 1.0f - 2.0f * __builtin_amdgcn_rcpf(e + 1.0f);
}

// Split fp32 into truncated-bf16 hi + truncated-bf16 lo (residual <= 2^-16 rel).
__device__ __forceinline__ void bf16_split(float y, unsigned short& h, unsigned short& lo) {
    unsigned int bits = __float_as_uint(y);
    h = (unsigned short)(bits >> 16);
    float r = y - __uint_as_float(bits & 0xffff0000u);
    lo = (unsigned short)(__float_as_uint(r) >> 16);
}

// Byte offset of (p, c) in a [PTILE][CC] ushort LDS plane, XOR-swizzled on the
// row index p. Reads (16 rows x 16B) and publishes (16 rows x 8B) both land
// ~2-way on banks (free per m136).
__device__ __forceinline__ int xb_off(int p, int c) {
    return (p * 256 + c * 2) ^ ((p & 7) << 4) ^ ((p & 8) << 3);
}

// LDS-only barrier: waits own DS ops, does NOT drain vmcnt (global stores stay
// in flight across steps). sched_barrier fences per guide rule #18.
__device__ __forceinline__ void lds_barrier() {
    asm volatile("s_waitcnt lgkmcnt(0)" ::: "memory");
    __builtin_amdgcn_sched_barrier(0);
    __builtin_amdgcn_s_barrier();
    __builtin_amdgcn_sched_barrier(0);
}

// ---- single fused kernel: 8-step Euler, split-bf16 MFMA ----------------------
// Block owns (b, 64-position tile) x all 128 channels. A=W, B=X: D[row=d][col=p],
// so the LDS publish is a row-contiguous ushort4 and global stores coalesce
// across the 16 lr-lanes (64B bursts, L2 assembles full lines).
// Wave w: d-tiles {2w,2w+1} x p-tiles {0..3} = 8 acc tiles, 96 MFMA/step.
__global__ __launch_bounds__(256) void euler_fused(
    const float* __restrict__ z, const float* __restrict__ W,
    const float* __restrict__ bias, float* __restrict__ out)
{
    __shared__ unsigned short XH[PTILE * CC];    // 16 KB bf16-hi state, [p][c] swizzled
    __shared__ unsigned short XL[PTILE * CC];    // 16 KB bf16-lo state

    const int b   = blockIdx.y;
    const int p0  = blockIdx.x * PTILE;
    const int tid = threadIdx.x;
    const int w   = tid >> 6;          // wave 0..3 -> d-tiles {2w, 2w+1}
    const int lr  = tid & 15;          // lane&15: A-row (=d) / B-col (=p) / D-col (=p)
    const int lh  = (tid >> 4) & 3;    // lane>>4: k-group / D-row-group

    // ---- W fragments split in-register from fp32 (A operand: A[row=d][k=c]) ----
    union BF8 { bf16x8 v; unsigned short u[8]; };
    bf16x8 wh[2][4], wl[2][4];
    #pragma unroll
    for (int dt = 0; dt < 2; ++dt) {
        const int d = (2 * w + dt) * 16 + lr;
        #pragma unroll
        for (int ks = 0; ks < 4; ++ks) {
            const float* wp = W + d * CC + ks * 32 + lh * 8;
            f32x4 f0 = *(const f32x4*)wp;
            f32x4 f1 = *(const f32x4*)(wp + 4);
            BF8 th, tl;
            #pragma unroll
            for (int e = 0; e < 4; ++e) bf16_split(f0[e], th.u[e],     tl.u[e]);
            #pragma unroll
            for (int e = 0; e < 4; ++e) bf16_split(f1[e], th.u[4 + e], tl.u[4 + e]);
            wh[dt][ks] = th.v;
            wl[dt][ks] = tl.v;
        }
    }

    // bias per D-row: d = (2w+dt)*16 + lh*4 + j
    float bv[2][4];
    #pragma unroll
    for (int dt = 0; dt < 2; ++dt)
        #pragma unroll
        for (int j = 0; j < 4; ++j)
            bv[dt][j] = bias[(2 * w + dt) * 16 + lh * 4 + j];

    // ---- prologue: cooperative z-tile load -> chunk-0 outputs + XH/XL ----
    const float* zb = z + (size_t)b * CC * PP + p0;
    #pragma unroll
    for (int it = 0; it < 8; ++it) {
        int slot = it * 256 + tid;                  // 2048 float4 slots
        int c  = slot >> 4;                         // 16 float4 per 64-pos row
        int po = (slot & 15) * 4;
        f32x4 v = *(const f32x4*)(zb + (size_t)c * PP + po);
        size_t o = (size_t)(b * CC + c) * PP + p0 + po;
        *(f32x4*)(out + o)                     = v;   // z_shift chunk 0 (= z)
        *(f32x4*)(out + (size_t)9 * CHUNK + o) = v;   // z_cls   chunk 0 (= z)
        #pragma unroll
        for (int e = 0; e < 4; ++e) {
            unsigned short h, lo;
            bf16_split(v[e], h, lo);
            int off = xb_off(po + e, c);
            *(unsigned short*)((char*)XH + off) = h;
            *(unsigned short*)((char*)XL + off) = lo;
        }
    }

    // ---- fp32 state in registers at this lane's D-layout slots:
    // st[pt][dt][j] = X[d = (2w+dt)*16 + lh*4 + j][p = p0 + pt*16 + lr]
    float st[4][2][4];
    #pragma unroll
    for (int pt = 0; pt < 4; ++pt)
        #pragma unroll
        for (int dt = 0; dt < 2; ++dt)
            #pragma unroll
            for (int j = 0; j < 4; ++j)
                st[pt][dt][j] =
                    z[(size_t)(b * CC + (2 * w + dt) * 16 + lh * 4 + j) * PP + p0 + pt * 16 + lr];

    lds_barrier();

    const int swz = ((lr & 7) << 4) ^ ((lr & 8) << 3);

    #pragma unroll
    for (int i = 1; i <= NSTEP; ++i) {
        f32x4 acc[4][2];
        #pragma unroll
        for (int pt = 0; pt < 4; ++pt)
            #pragma unroll
            for (int dt = 0; dt < 2; ++dt)
                acc[pt][dt] = (f32x4){0.0f, 0.0f, 0.0f, 0.0f};

        // ---- channel matmul: acc = Wh*Xh + Wh*Xl + Wl*Xh (fp32 accum) ----
        // B-frag (X): col p = pt*16+lr, k = c contiguous; reads identical to v3.
        #pragma unroll
        for (int pt = 0; pt < 4; ++pt) {
            #pragma unroll
            for (int ks = 0; ks < 4; ++ks) {
                const int ro = ((pt * 16 + lr) * 256 + ks * 64 + lh * 16) ^ swz;
                bf16x8 bh = *(const bf16x8*)((const char*)XH + ro);
                bf16x8 bl = *(const bf16x8*)((const char*)XL + ro);
                #pragma unroll
                for (int dt = 0; dt < 2; ++dt) {
                    acc[pt][dt] = __builtin_amdgcn_mfma_f32_16x16x32_bf16(wh[dt][ks], bh, acc[pt][dt], 0, 0, 0);
                    acc[pt][dt] = __builtin_amdgcn_mfma_f32_16x16x32_bf16(wh[dt][ks], bl, acc[pt][dt], 0, 0, 0);
                    acc[pt][dt] = __builtin_amdgcn_mfma_f32_16x16x32_bf16(wl[dt][ks], bh, acc[pt][dt], 0, 0, 0);
                }
            }
        }

        // ---- y = x_old + tanh(acc + bias); state stays in registers ----
        #pragma unroll
        for (int pt = 0; pt < 4; ++pt)
            #pragma unroll
            for (int dt = 0; dt < 2; ++dt)
                #pragma unroll
                for (int j = 0; j < 4; ++j)
                    st[pt][dt][j] += fast_tanh(acc[pt][dt][j] + bv[dt][j]);

        if (i < NSTEP) {
            lds_barrier();   // all reads of old state done before overwrite

            // ---- publish new bf16 hi/lo state: row-contiguous ushort4 ----
            #pragma unroll
            for (int pt = 0; pt < 4; ++pt)
                #pragma unroll
                for (int dt = 0; dt < 2; ++dt) {
                    ushort4 hv, lv;
                    bf16_split(st[pt][dt][0], hv.x, lv.x);
                    bf16_split(st[pt][dt][1], hv.y, lv.y);
                    bf16_split(st[pt][dt][2], hv.z, lv.z);
                    bf16_split(st[pt][dt][3], hv.w, lv.w);
                    const int off = xb_off(pt * 16 + lr, (2 * w + dt) * 16 + lh * 4);
                    *(ushort4*)((char*)XH + off) = hv;
                    *(ushort4*)((char*)XL + off) = lv;
                }

            lds_barrier();   // publish visible; stores below overlap next step
        }

        // ---- global stores for chunk i (cached, fire-and-forget) ----
        // Coalesced across lr-lanes: 16 consecutive p per 64B burst, per d row.
        const size_t shiftBase = (size_t)i * CHUNK;
        const size_t clsBase   = (size_t)(9 + i) * CHUNK;
        const int s = VV * i;   // flat-position shift (t -> t+i)
        const bool fast = (p0 >= s) && (p0 + PTILE - 1 + s < PP);   // block-uniform
        #pragma unroll
        for (int pt = 0; pt < 4; ++pt) {
            const int p = p0 + pt * 16 + lr;
            #pragma unroll
            for (int dt = 0; dt < 2; ++dt) {
                #pragma unroll
                for (int j = 0; j < 4; ++j) {
                    const int d = (2 * w + dt) * 16 + lh * 4 + j;
                    const size_t row = (size_t)(b * CC + d) * PP;
                    const float y = st[pt][dt][j];
                    out[clsBase + row + p] = y;                       // z_cls chunk i
                    if (fast) {
                        out[shiftBase + row + p + s] = y;             // z_shift chunk i
                    } else {
                        const int q = p + s;
                        if (q < PP) out[shiftBase + row + q] = y;
                        if (p < s)  out[shiftBase + row + p] = 0.0f;  // leading zeros
                    }
                }
            }
        }
    }
}

extern "C" void kernel_launch(void* const* d_in, const int* in_sizes, int n_in,
                              void* d_out, int out_size, void* d_ws, size_t ws_size,
                              hipStream_t stream) {
    const float* z    = (const float*)d_in[0];   // (32,128,64,25) fp32
    const float* W    = (const float*)d_in[1];   // (128,128) fp32
    const float* bias = (const float*)d_in[2];   // (128,) fp32
    float* out = (float*)d_out;                  // 18 * CHUNK fp32

    hipLaunchKernelGGL(euler_fused, dim3(NPT, BB), dim3(256), 0, stream, z, W, bias, out);
}